// Round 22
// baseline (230.815 us; speedup 1.0000x reference)
//
#include <hip/hip_runtime.h>
#include <hip/hip_bf16.h>

#define T_TOK 2048
#define DDIM  1024
#define HDIM  2048
#define NEXP  8
#define NSEG  9   // 8 routed + 1 shared

typedef unsigned short u16;
typedef __attribute__((ext_vector_type(4))) float f32x4;
typedef __attribute__((ext_vector_type(8))) short bf16x8;
typedef __attribute__((ext_vector_type(4))) unsigned short u16x4;
typedef __attribute__((ext_vector_type(8))) unsigned short u16x8;

__device__ __forceinline__ u16 f2bf(float x) {
  union { float f; unsigned int u; } v; v.f = x;
  unsigned int r = v.u + 0x7fffu + ((v.u >> 16) & 1u);
  return (u16)(r >> 16);
}
// tanh-form gelu via sigmoid: max |err| vs exact ~0.003 << 0.038 threshold
__device__ __forceinline__ float gelu_fast(float x) {
  float y = x * (1.595769122f + 0.0713548162f * x * x);
  return x / (1.0f + __expf(-y));
}
// chunk swizzle for 64B rows (4 x 16B chunks)
__device__ __forceinline__ int swz4(int row) {
  return (row & 3) ^ ((row >> 2) & 3);
}

__device__ __forceinline__ void gload16(const void* g, void* l) {
  __builtin_amdgcn_global_load_lds(
      (const __attribute__((address_space(1))) unsigned int*)g,
      (__attribute__((address_space(3))) unsigned int*)l, 16, 0, 0);
}

// ---------------- router + fused seg (last-block-done ticket) ----------------
// counts[0..8]: per-expert counters; counts[12]: done-block ticket.
// The LAST router block to finish (device-scope atomic ticket) computes
// segoff / ytab / nyt after a __threadfence -- removes the separate
// seg_kernel dispatch and its launch/serialization bubble.
__global__ __launch_bounds__(256) void router_kernel(
    const float* __restrict__ x, const float* __restrict__ rw,
    const float* __restrict__ rb, u16* __restrict__ xb,
    float* __restrict__ weights, int* __restrict__ counts,
    int* __restrict__ lists, int* __restrict__ segoff,
    int* __restrict__ ytab, int* __restrict__ nyt)
{
  int wv = threadIdx.x >> 6, lane = threadIdx.x & 63;
  int t = blockIdx.x * 4 + wv;            // one wave per token
  const float* xrow = x + (size_t)t * DDIM;
  float acc[NEXP];
#pragma unroll
  for (int e = 0; e < NEXP; e++) acc[e] = 0.f;
#pragma unroll
  for (int i = 0; i < 4; i++) {
    int d0 = i * 256 + lane * 4;
    f32x4 xv = *(const f32x4*)(xrow + d0);
    u16x4 pk;
#pragma unroll
    for (int j = 0; j < 4; j++) {
      float xs = xv[j];
      pk[j] = f2bf(xs);
      const float* wr = rw + (size_t)(d0 + j) * NEXP;
#pragma unroll
      for (int e = 0; e < NEXP; e++) acc[e] = fmaf(xs, wr[e], acc[e]);
    }
    *(u16x4*)(xb + (size_t)t * DDIM + d0) = pk;
  }
#pragma unroll
  for (int off = 32; off >= 1; off >>= 1)
#pragma unroll
    for (int e = 0; e < NEXP; e++) acc[e] += __shfl_xor(acc[e], off);

  if (lane == 0) {
    float lg[NEXP], mx = -1e30f;
#pragma unroll
    for (int e = 0; e < NEXP; e++) { lg[e] = acc[e] + rb[e]; mx = fmaxf(mx, lg[e]); }
    float p[NEXP], s = 0.f;
#pragma unroll
    for (int e = 0; e < NEXP; e++) { p[e] = expf(lg[e] - mx); s += p[e]; }
    float inv = 1.0f / s;
#pragma unroll
    for (int e = 0; e < NEXP; e++) p[e] *= inv;
    int i1 = 0;
#pragma unroll
    for (int e = 1; e < NEXP; e++) if (p[e] > p[i1]) i1 = e;
    int i2 = (i1 == 0) ? 1 : 0;
#pragma unroll
    for (int e = 0; e < NEXP; e++) if (e != i1 && p[e] > p[i2]) i2 = e;
#pragma unroll
    for (int e = 0; e < NEXP; e++)
      weights[(size_t)t * NEXP + e] = (e == i1) ? p[i1] : (e == i2) ? p[i2] : 0.f;
    int p1 = atomicAdd(counts + i1, 1); lists[i1 * T_TOK + p1] = t;
    int p2 = atomicAdd(counts + i2, 1); lists[i2 * T_TOK + p2] = t;
    lists[NEXP * T_TOK + t] = t;        // shared segment: identity
  }

  // ---- fused seg: last block to finish builds the tile tables ----
  __syncthreads();                      // all this block's atomics issued
  if (threadIdx.x == 0) {
    __threadfence();                    // publish this block's writes
    int ticket = atomicAdd(counts + 12, 1);
    if (ticket == gridDim.x - 1) {      // I am the last block
      __threadfence();                  // acquire all blocks' writes
      int off = 0, n = 0;
      for (int e = 0; e < NSEG; e++) {
        segoff[e] = off;
        int c = (e < NEXP) ? counts[e] : T_TOK;
        for (int my = 0; my * 256 < c; my++) ytab[n++] = e * 256 + my;
        off += c;
      }
      nyt[0] = n;
      __threadfence();                  // publish tables before kernel end
    }
  }
}

// =====================================================================
// GEMM1 = round-17/19 proven kernel VERBATIM (103 us, 0 bank conflicts):
// BM=256 x BN=128, BK=64, 8 waves 4Mx2N, 48 KB LDS, 2-sync schedule,
// fused fp32->bf16 B with conflict-free staging.
// =====================================================================
__global__ __launch_bounds__(512) void gemm1_kernel(
    const u16* __restrict__ Xb, const float* __restrict__ rw1,
    const float* __restrict__ sw1, const float* __restrict__ rb1,
    const float* __restrict__ sb1, const int* __restrict__ counts,
    const int* __restrict__ segoff, const int* __restrict__ lists,
    const int* __restrict__ ytab, const int* __restrict__ nyt,
    u16* __restrict__ H1)
{
  __shared__ u16 Alds[256 * 64];   // [m][k] 32 KB
  __shared__ u16 Blds[128 * 64];   // [n][k] 16 KB

  int tid = threadIdx.x, lane = tid & 63;
  int wv = tid >> 6, wm = wv >> 1, wn = wv & 1;
  int kc = lane >> 4, lr = lane & 15;

  int srow[4], achk[4];
#pragma unroll
  for (int r = 0; r < 4; r++) {
    int i = r * 512 + tid;
    srow[r] = i >> 3;
    achk[r] = ((i & 7) ^ ((i >> 3) & 7)) * 8;
  }
  int aoff[2][4], boff[2][4];
#pragma unroll
  for (int ks = 0; ks < 2; ks++)
#pragma unroll
    for (int f = 0; f < 4; f++) {
      int ra = wm * 64 + f * 16 + lr;     // 0..255
      int rb_ = wn * 64 + f * 16 + lr;    // 0..127
      aoff[ks][f] = ra * 64 + (((ks * 4 + kc) ^ (ra & 7)) * 8);
      boff[ks][f] = rb_ * 64 + (((ks * 4 + kc) ^ (rb_ & 7)) * 8);
    }
  int bchk = (wv ^ (lane & 7)) * 8;

  int ntile = nyt[0] * (HDIM / 128);   // nyt * 16
  for (int t = blockIdx.x; t < ntile; t += gridDim.x) {
    int yt = t >> 4, nx = t & 15;
    int em = ytab[yt];
    int e = em >> 8, m0 = (em & 255) * 256, n0 = nx * 128;
    int cnt = counts[e] < T_TOK && e < NEXP ? counts[e] : (e < NEXP ? counts[e] : T_TOK);
    cnt = (e < NEXP) ? counts[e] : T_TOK;
    const float* Wf = (e < NEXP) ? (rw1 + (size_t)e * DDIM * HDIM) : sw1;
    const float* bias = (e < NEXP) ? (rb1 + (size_t)e * HDIM) : sb1;
    const int* list = lists + e * T_TOK;
    int seg = segoff[e];

    size_t asrc[4];
#pragma unroll
    for (int r = 0; r < 4; r++) {
      int tok = list[min(m0 + srow[r], cnt - 1)];
      asrc[r] = (size_t)tok * DDIM + achk[r];
    }
    const float* Wbase = Wf + n0 + lane;

    f32x4 acc[4][4];
#pragma unroll
    for (int i = 0; i < 4; i++)
#pragma unroll
      for (int j = 0; j < 4; j++) acc[i][j] = (f32x4){0.f, 0.f, 0.f, 0.f};

    float vb0[8], vb1[8];
    {
      const float* Wk = Wbase + (size_t)(wv * 8) * HDIM;
#pragma unroll
      for (int q = 0; q < 8; q++) {
        vb0[q] = Wk[(size_t)q * HDIM];
        vb1[q] = Wk[(size_t)q * HDIM + 64];
      }
    }

    const int NS = DDIM / 64;   // 16 steps
    for (int s = 0; s < NS; s++) {
      int kk = s * 64;
#pragma unroll
      for (int r = 0; r < 4; r++)
        gload16(Xb + asrc[r] + kk, Alds + (size_t)(r * 512 + tid) * 8);
      {
        u16x8 pk0, pk1;
#pragma unroll
        for (int q = 0; q < 8; q++) { pk0[q] = f2bf(vb0[q]); pk1[q] = f2bf(vb1[q]); }
        *(u16x8*)(Blds + (size_t)lane * 64 + bchk) = pk0;
        *(u16x8*)(Blds + (size_t)(lane + 64) * 64 + bchk) = pk1;
      }
      __syncthreads();
      if (s + 1 < NS) {
        const float* Wk = Wbase + (size_t)((s + 1) * 64 + wv * 8) * HDIM;
#pragma unroll
        for (int q = 0; q < 8; q++) {
          vb0[q] = Wk[(size_t)q * HDIM];
          vb1[q] = Wk[(size_t)q * HDIM + 64];
        }
      }
#pragma unroll
      for (int ks = 0; ks < 2; ks++) {
        bf16x8 af[4], bfr[4];
#pragma unroll
        for (int f = 0; f < 4; f++) {
          af[f]  = *(const bf16x8*)(Alds + aoff[ks][f]);
          bfr[f] = *(const bf16x8*)(Blds + boff[ks][f]);
        }
#pragma unroll
        for (int mf = 0; mf < 4; mf++)
#pragma unroll
          for (int nf = 0; nf < 4; nf++)
            acc[mf][nf] = __builtin_amdgcn_mfma_f32_16x16x32_bf16(af[mf], bfr[nf], acc[mf][nf], 0, 0, 0);
      }
      __syncthreads();
    }

#pragma unroll
    for (int nf = 0; nf < 4; nf++) {
      int col = n0 + wn * 64 + nf * 16 + lr;
      float b = bias[col];
#pragma unroll
      for (int mf = 0; mf < 4; mf++) {
#pragma unroll
        for (int rg = 0; rg < 4; rg++) {
          int mt = wm * 64 + mf * 16 + kc * 4 + rg;
          if (m0 + mt < cnt) {
            float v = acc[mf][nf][rg] + b;
            H1[(size_t)(seg + m0 + mt) * HDIM + col] = f2bf(gelu_fast(v));
          }
        }
      }
    }
  }
}

// =====================================================================
// GEMM2 = round-14/19 proven kernel VERBATIM: 256x256, BK=32, 8 waves
// 2Mx4N, depth-2 A prefetch (4-buf gload_lds), fused fp32->bf16 W2
// staging (2-buf, cvt pre-barrier), counted vmcnt 8/6/0, lgkmcnt(0),
// one raw barrier per K-step, K split x2, atomicAdd epilogue.
// =====================================================================
__global__ __launch_bounds__(512) void gemm2_kernel(
    const u16* __restrict__ H1, const float* __restrict__ rw2,
    const float* __restrict__ sw2, const float* __restrict__ rb2,
    const float* __restrict__ sb2, const float* __restrict__ weights,
    const int* __restrict__ counts, const int* __restrict__ segoff,
    const int* __restrict__ lists, const int* __restrict__ ytab,
    const int* __restrict__ nyt, float* __restrict__ out)
{
  __shared__ u16 Alds[4][256 * 32];
  __shared__ u16 Blds[2][256 * 32];

  int tid = threadIdx.x, lane = tid & 63;
  int wv = tid >> 6, wm = wv >> 2, wn = wv & 3;
  int kc = lane >> 4, lr = lane & 15;

  int srow[2], soff[2];
#pragma unroll
  for (int j = 0; j < 2; j++) {
    int i = j * 512 + tid;
    srow[j] = i >> 2;
    soff[j] = (((i & 3) ^ swz4(i >> 2)) * 8);
  }
  int aoff[8], boff[4];
#pragma unroll
  for (int f = 0; f < 8; f++) {
    int ra = wm * 128 + f * 16 + lr;
    aoff[f] = ra * 32 + ((kc ^ swz4(ra)) * 8);
  }
#pragma unroll
  for (int f = 0; f < 4; f++) {
    int rb_ = wn * 64 + f * 16 + lr;
    boff[f] = rb_ * 32 + ((kc ^ swz4(rb_)) * 8);
  }
  int bw[4];
#pragma unroll
  for (int j = 0; j < 4; j++)
    bw[j] = ((lane << 2) + j) * 32 + (((wv >> 1) ^ j ^ (lane & 3)) << 3) + ((wv & 1) << 2);

  int ntile = nyt[0] * (DDIM / 256) * 2;
  for (int t = blockIdx.x; t < ntile; t += gridDim.x) {
    int kh = t & 1, nx = (t >> 1) & 3, yt = t >> 3;
    int em = ytab[yt];
    int e = em >> 8, m0 = (em & 255) * 256, n0 = nx * 256;
    int cnt = (e < NEXP) ? counts[e] : T_TOK;
    const float* Wf = (e < NEXP) ? (rw2 + (size_t)e * HDIM * DDIM) : sw2;
    const float* bias = (e < NEXP) ? (rb2 + (size_t)e * DDIM) : sb2;
    const int* list = lists + e * T_TOK;
    int seg = segoff[e];
    int k0 = kh * 1024;

    size_t abase[2];
#pragma unroll
    for (int j = 0; j < 2; j++)
      abase[j] = (size_t)(seg + min(m0 + srow[j], cnt - 1)) * HDIM + k0 + soff[j];
    const float* Wb = Wf + (size_t)k0 * DDIM + n0 + (lane << 2);

    f32x4 acc[8][4];
#pragma unroll
    for (int i = 0; i < 8; i++)
#pragma unroll
      for (int j = 0; j < 4; j++) acc[i][j] = (f32x4){0.f, 0.f, 0.f, 0.f};

    const int NS = 1024 / 32;   // 32 steps
    f32x4 vBa, vBb, vBc, vBd;
    {
      const float* Wk = Wb + (size_t)(wv * 4) * DDIM;
      vBa = *(const f32x4*)(Wk);
      vBb = *(const f32x4*)(Wk + DDIM);
      vBc = *(const f32x4*)(Wk + 2 * DDIM);
      vBd = *(const f32x4*)(Wk + 3 * DDIM);
    }
#pragma unroll
    for (int s = 0; s < 2; s++)
#pragma unroll
      for (int j = 0; j < 2; j++) {
        int i = j * 512 + tid;
        gload16(H1 + abase[j] + s * 32, &Alds[s][i * 8]);
      }

    for (int s = 0; s < NS; s++) {
      if (s + 2 < NS) {
        int kk = (s + 2) * 32;
        int nb = (s + 2) & 3;
#pragma unroll
        for (int j = 0; j < 2; j++) {
          int i = j * 512 + tid;
          gload16(H1 + abase[j] + kk, &Alds[nb][i * 8]);
        }
      }
      {
        u16* Bd = &Blds[s & 1][0];
#pragma unroll
        for (int j = 0; j < 4; j++) {
          u16x4 pk;
          pk[0] = f2bf(vBa[j]); pk[1] = f2bf(vBb[j]);
          pk[2] = f2bf(vBc[j]); pk[3] = f2bf(vBd[j]);
          *(u16x4*)(Bd + bw[j]) = pk;
        }
      }
      if (s + 1 < NS) {
        const float* Wk = Wb + (size_t)((s + 1) * 32 + wv * 4) * DDIM;
        vBa = *(const f32x4*)(Wk);
        vBb = *(const f32x4*)(Wk + DDIM);
        vBc = *(const f32x4*)(Wk + 2 * DDIM);
        vBd = *(const f32x4*)(Wk + 3 * DDIM);
      }
      if (s + 2 < NS)      asm volatile("s_waitcnt vmcnt(8)" ::: "memory");
      else if (s + 1 < NS) asm volatile("s_waitcnt vmcnt(6)" ::: "memory");
      else                 asm volatile("s_waitcnt vmcnt(0)" ::: "memory");
      asm volatile("s_waitcnt lgkmcnt(0)" ::: "memory");
      __builtin_amdgcn_s_barrier();
      __builtin_amdgcn_sched_barrier(0);

      const u16* Ac = &Alds[s & 3][0];
      const u16* Bc = &Blds[s & 1][0];
      bf16x8 af[8], bfr[4];
#pragma unroll
      for (int f = 0; f < 8; f++) af[f] = *(const bf16x8*)(Ac + aoff[f]);
#pragma unroll
      for (int f = 0; f < 4; f++) bfr[f] = *(const bf16x8*)(Bc + boff[f]);
      __builtin_amdgcn_s_setprio(1);
#pragma unroll
      for (int mf = 0; mf < 8; mf++)
#pragma unroll
        for (int nf = 0; nf < 4; nf++)
          acc[mf][nf] = __builtin_amdgcn_mfma_f32_16x16x32_bf16(af[mf], bfr[nf], acc[mf][nf], 0, 0, 0);
      __builtin_amdgcn_s_setprio(0);
    }

    float biasv[4];
#pragma unroll
    for (int nf = 0; nf < 4; nf++)
      biasv[nf] = (kh == 0) ? bias[n0 + wn * 64 + nf * 16 + lr] : 0.f;

#pragma unroll
    for (int mf = 0; mf < 8; mf++) {
#pragma unroll
      for (int rg = 0; rg < 4; rg++) {
        int mt = wm * 128 + mf * 16 + kc * 4 + rg;
        int mrow = m0 + mt;
        if (mrow < cnt) {
          int tok = list[mrow];
          float w = (e < NEXP) ? weights[(size_t)tok * NEXP + e] : 1.0f;
          float* orow = out + (size_t)tok * DDIM + n0 + wn * 64 + lr;
#pragma unroll
          for (int nf = 0; nf < 4; nf++)
            atomicAdd(orow + nf * 16, w * (acc[mf][nf][rg] + biasv[nf]));
        }
      }
    }
    __builtin_amdgcn_s_barrier();
    __builtin_amdgcn_sched_barrier(0);
  }
}

// ---------------- launcher ----------------
extern "C" void kernel_launch(void* const* d_in, const int* in_sizes, int n_in,
                              void* d_out, int out_size, void* d_ws, size_t ws_size,
                              hipStream_t stream) {
  (void)in_sizes; (void)n_in; (void)out_size; (void)ws_size;
  const float* hidden   = (const float*)d_in[0];
  const float* router_w = (const float*)d_in[1];
  const float* router_b = (const float*)d_in[2];
  const float* sw1 = (const float*)d_in[3];
  const float* sb1 = (const float*)d_in[4];
  const float* sw2 = (const float*)d_in[5];
  const float* sb2 = (const float*)d_in[6];
  const float* rw1 = (const float*)d_in[7];
  const float* rb1 = (const float*)d_in[8];
  const float* rw2 = (const float*)d_in[9];
  const float* rb2 = (const float*)d_in[10];
  float* out = (float*)d_out;

  char* ws = (char*)d_ws;
  u16* Xb      = (u16*)(ws + 0);            //  4,194,304  [T][D] bf16
  u16* H1      = (u16*)(ws + 4194304);      // 25,165,824  [6144][H] bf16
  float* weights = (float*)(ws + 29360128); //     65,536  [T][E]
  int* counts  = (int*)(ws + 29425664);     //         64 (counts[12] = ticket)
  int* segoff  = (int*)(ws + 29425728);     //         64
  int* lists   = (int*)(ws + 29425792);     //     73,728  [NSEG][T]
  int* ytab    = (int*)(ws + 29499520);     //        640
  int* nyt     = (int*)(ws + 29500160);     //          4

  hipMemsetAsync(counts, 0, 64, stream);
  hipMemsetAsync(out, 0, (size_t)T_TOK * DDIM * sizeof(float), stream);

  router_kernel<<<T_TOK / 4, 256, 0, stream>>>(hidden, router_w, router_b, Xb,
                                               weights, counts, lists,
                                               segoff, ytab, nyt);

  gemm1_kernel<<<512, 512, 0, stream>>>(
      Xb, rw1, sw1, rb1, sb1, counts, segoff, lists, ytab, nyt, H1);
  gemm2_kernel<<<256, 512, 0, stream>>>(
      H1, rw2, sw2, rb2, sb2, weights, counts, segoff, lists, ytab, nyt, out);
}

// Round 23
// 223.910 us; speedup vs baseline: 1.0308x; 1.0308x over previous
//
#include <hip/hip_runtime.h>
#include <hip/hip_bf16.h>

#define T_TOK 2048
#define DDIM  1024
#define HDIM  2048
#define NEXP  8
#define NSEG  9   // 8 routed + 1 shared

typedef unsigned short u16;
typedef __attribute__((ext_vector_type(4))) float f32x4;
typedef __attribute__((ext_vector_type(8))) short bf16x8;
typedef __attribute__((ext_vector_type(4))) unsigned short u16x4;
typedef __attribute__((ext_vector_type(8))) unsigned short u16x8;

__device__ __forceinline__ u16 f2bf(float x) {
  union { float f; unsigned int u; } v; v.f = x;
  unsigned int r = v.u + 0x7fffu + ((v.u >> 16) & 1u);
  return (u16)(r >> 16);
}
// tanh-form gelu via sigmoid: max |err| vs exact ~0.003 << 0.038 threshold
__device__ __forceinline__ float gelu_fast(float x) {
  float y = x * (1.595769122f + 0.0713548162f * x * x);
  return x / (1.0f + __expf(-y));
}
// chunk swizzle for 64B rows (4 x 16B chunks)
__device__ __forceinline__ int swz4(int row) {
  return (row & 3) ^ ((row >> 2) & 3);
}

__device__ __forceinline__ void gload16(const void* g, void* l) {
  __builtin_amdgcn_global_load_lds(
      (const __attribute__((address_space(1))) unsigned int*)g,
      (__attribute__((address_space(3))) unsigned int*)l, 16, 0, 0);
}

// ---------------- router: logits, softmax, top-2, lists, bf16 X ----------------
__global__ __launch_bounds__(256) void router_kernel(
    const float* __restrict__ x, const float* __restrict__ rw,
    const float* __restrict__ rb, u16* __restrict__ xb,
    float* __restrict__ weights, int* __restrict__ counts,
    int* __restrict__ lists)
{
  int wv = threadIdx.x >> 6, lane = threadIdx.x & 63;
  int t = blockIdx.x * 4 + wv;            // one wave per token
  const float* xrow = x + (size_t)t * DDIM;
  float acc[NEXP];
#pragma unroll
  for (int e = 0; e < NEXP; e++) acc[e] = 0.f;
#pragma unroll
  for (int i = 0; i < 4; i++) {
    int d0 = i * 256 + lane * 4;
    f32x4 xv = *(const f32x4*)(xrow + d0);
    u16x4 pk;
#pragma unroll
    for (int j = 0; j < 4; j++) {
      float xs = xv[j];
      pk[j] = f2bf(xs);
      const float* wr = rw + (size_t)(d0 + j) * NEXP;
#pragma unroll
      for (int e = 0; e < NEXP; e++) acc[e] = fmaf(xs, wr[e], acc[e]);
    }
    *(u16x4*)(xb + (size_t)t * DDIM + d0) = pk;
  }
#pragma unroll
  for (int off = 32; off >= 1; off >>= 1)
#pragma unroll
    for (int e = 0; e < NEXP; e++) acc[e] += __shfl_xor(acc[e], off);

  if (lane == 0) {
    float lg[NEXP], mx = -1e30f;
#pragma unroll
    for (int e = 0; e < NEXP; e++) { lg[e] = acc[e] + rb[e]; mx = fmaxf(mx, lg[e]); }
    float p[NEXP], s = 0.f;
#pragma unroll
    for (int e = 0; e < NEXP; e++) { p[e] = expf(lg[e] - mx); s += p[e]; }
    float inv = 1.0f / s;
#pragma unroll
    for (int e = 0; e < NEXP; e++) p[e] *= inv;
    int i1 = 0;
#pragma unroll
    for (int e = 1; e < NEXP; e++) if (p[e] > p[i1]) i1 = e;
    int i2 = (i1 == 0) ? 1 : 0;
#pragma unroll
    for (int e = 0; e < NEXP; e++) if (e != i1 && p[e] > p[i2]) i2 = e;
#pragma unroll
    for (int e = 0; e < NEXP; e++)
      weights[(size_t)t * NEXP + e] = (e == i1) ? p[i1] : (e == i2) ? p[i2] : 0.f;
    int p1 = atomicAdd(counts + i1, 1); lists[i1 * T_TOK + p1] = t;
    int p2 = atomicAdd(counts + i2, 1); lists[i2 * T_TOK + p2] = t;
    lists[NEXP * T_TOK + t] = t;        // shared segment: identity
  }
}

// seg offsets + 256-row tile table (both GEMMs): em = e*256 + my
__global__ void seg_kernel(int* counts, int* segoff, int* ytab, int* nyt) {
  counts[NEXP] = T_TOK;
  int off = 0, n = 0;
  for (int e = 0; e < NSEG; e++) {
    segoff[e] = off;
    int c = counts[e];
    for (int my = 0; my * 256 < c; my++) ytab[n++] = e * 256 + my;
    off += c;
  }
  *nyt = n;
}

// =====================================================================
// GEMM1 = round-17 proven kernel VERBATIM (103 us, 0 bank conflicts):
// BM=256 x BN=128, BK=64, 8 waves 4Mx2N, 48 KB LDS, 2-sync schedule,
// fused fp32->bf16 B with conflict-free staging.
// =====================================================================
__global__ __launch_bounds__(512) void gemm1_kernel(
    const u16* __restrict__ Xb, const float* __restrict__ rw1,
    const float* __restrict__ sw1, const float* __restrict__ rb1,
    const float* __restrict__ sb1, const int* __restrict__ counts,
    const int* __restrict__ segoff, const int* __restrict__ lists,
    const int* __restrict__ ytab, const int* __restrict__ nyt,
    u16* __restrict__ H1)
{
  __shared__ u16 Alds[256 * 64];   // [m][k] 32 KB
  __shared__ u16 Blds[128 * 64];   // [n][k] 16 KB

  int tid = threadIdx.x, lane = tid & 63;
  int wv = tid >> 6, wm = wv >> 1, wn = wv & 1;
  int kc = lane >> 4, lr = lane & 15;

  int srow[4], achk[4];
#pragma unroll
  for (int r = 0; r < 4; r++) {
    int i = r * 512 + tid;
    srow[r] = i >> 3;
    achk[r] = ((i & 7) ^ ((i >> 3) & 7)) * 8;
  }
  int aoff[2][4], boff[2][4];
#pragma unroll
  for (int ks = 0; ks < 2; ks++)
#pragma unroll
    for (int f = 0; f < 4; f++) {
      int ra = wm * 64 + f * 16 + lr;     // 0..255
      int rb_ = wn * 64 + f * 16 + lr;    // 0..127
      aoff[ks][f] = ra * 64 + (((ks * 4 + kc) ^ (ra & 7)) * 8);
      boff[ks][f] = rb_ * 64 + (((ks * 4 + kc) ^ (rb_ & 7)) * 8);
    }
  int bchk = (wv ^ (lane & 7)) * 8;

  int ntile = nyt[0] * (HDIM / 128);   // nyt * 16
  for (int t = blockIdx.x; t < ntile; t += gridDim.x) {
    int yt = t >> 4, nx = t & 15;
    int em = ytab[yt];
    int e = em >> 8, m0 = (em & 255) * 256, n0 = nx * 128;
    int cnt = counts[e];
    const float* Wf = (e < NEXP) ? (rw1 + (size_t)e * DDIM * HDIM) : sw1;
    const float* bias = (e < NEXP) ? (rb1 + (size_t)e * HDIM) : sb1;
    const int* list = lists + e * T_TOK;
    int seg = segoff[e];

    size_t asrc[4];
#pragma unroll
    for (int r = 0; r < 4; r++) {
      int tok = list[min(m0 + srow[r], cnt - 1)];
      asrc[r] = (size_t)tok * DDIM + achk[r];
    }
    const float* Wbase = Wf + n0 + lane;

    f32x4 acc[4][4];
#pragma unroll
    for (int i = 0; i < 4; i++)
#pragma unroll
      for (int j = 0; j < 4; j++) acc[i][j] = (f32x4){0.f, 0.f, 0.f, 0.f};

    float vb0[8], vb1[8];
    {
      const float* Wk = Wbase + (size_t)(wv * 8) * HDIM;
#pragma unroll
      for (int q = 0; q < 8; q++) {
        vb0[q] = Wk[(size_t)q * HDIM];
        vb1[q] = Wk[(size_t)q * HDIM + 64];
      }
    }

    const int NS = DDIM / 64;   // 16 steps
    for (int s = 0; s < NS; s++) {
      int kk = s * 64;
#pragma unroll
      for (int r = 0; r < 4; r++)
        gload16(Xb + asrc[r] + kk, Alds + (size_t)(r * 512 + tid) * 8);
      {
        u16x8 pk0, pk1;
#pragma unroll
        for (int q = 0; q < 8; q++) { pk0[q] = f2bf(vb0[q]); pk1[q] = f2bf(vb1[q]); }
        *(u16x8*)(Blds + (size_t)lane * 64 + bchk) = pk0;
        *(u16x8*)(Blds + (size_t)(lane + 64) * 64 + bchk) = pk1;
      }
      __syncthreads();
      if (s + 1 < NS) {
        const float* Wk = Wbase + (size_t)((s + 1) * 64 + wv * 8) * HDIM;
#pragma unroll
        for (int q = 0; q < 8; q++) {
          vb0[q] = Wk[(size_t)q * HDIM];
          vb1[q] = Wk[(size_t)q * HDIM + 64];
        }
      }
#pragma unroll
      for (int ks = 0; ks < 2; ks++) {
        bf16x8 af[4], bfr[4];
#pragma unroll
        for (int f = 0; f < 4; f++) {
          af[f]  = *(const bf16x8*)(Alds + aoff[ks][f]);
          bfr[f] = *(const bf16x8*)(Blds + boff[ks][f]);
        }
#pragma unroll
        for (int mf = 0; mf < 4; mf++)
#pragma unroll
          for (int nf = 0; nf < 4; nf++)
            acc[mf][nf] = __builtin_amdgcn_mfma_f32_16x16x32_bf16(af[mf], bfr[nf], acc[mf][nf], 0, 0, 0);
      }
      __syncthreads();
    }

#pragma unroll
    for (int nf = 0; nf < 4; nf++) {
      int col = n0 + wn * 64 + nf * 16 + lr;
      float b = bias[col];
#pragma unroll
      for (int mf = 0; mf < 4; mf++) {
#pragma unroll
        for (int rg = 0; rg < 4; rg++) {
          int mt = wm * 64 + mf * 16 + kc * 4 + rg;
          if (m0 + mt < cnt) {
            float v = acc[mf][nf][rg] + b;
            H1[(size_t)(seg + m0 + mt) * HDIM + col] = f2bf(gelu_fast(v));
          }
        }
      }
    }
  }
}

// =====================================================================
// GEMM2 = round-14 proven kernel VERBATIM (the form in the two best
// totals; FETCH 65 MB): 256x256, BK=32, 8 waves 2Mx4N, depth-2 A
// prefetch (4-buf gload_lds), fused fp32->bf16 W2 staging (2-buf,
// cvt pre-barrier), counted vmcnt 8/6/0, lgkmcnt(0), one raw barrier
// per K-step, K split x2, atomicAdd epilogue.
// =====================================================================
__global__ __launch_bounds__(512) void gemm2_kernel(
    const u16* __restrict__ H1, const float* __restrict__ rw2,
    const float* __restrict__ sw2, const float* __restrict__ rb2,
    const float* __restrict__ sb2, const float* __restrict__ weights,
    const int* __restrict__ counts, const int* __restrict__ segoff,
    const int* __restrict__ lists, const int* __restrict__ ytab,
    const int* __restrict__ nyt, float* __restrict__ out)
{
  __shared__ u16 Alds[4][256 * 32];
  __shared__ u16 Blds[2][256 * 32];

  int tid = threadIdx.x, lane = tid & 63;
  int wv = tid >> 6, wm = wv >> 2, wn = wv & 3;
  int kc = lane >> 4, lr = lane & 15;

  int srow[2], soff[2];
#pragma unroll
  for (int j = 0; j < 2; j++) {
    int i = j * 512 + tid;
    srow[j] = i >> 2;
    soff[j] = (((i & 3) ^ swz4(i >> 2)) * 8);
  }
  int aoff[8], boff[4];
#pragma unroll
  for (int f = 0; f < 8; f++) {
    int ra = wm * 128 + f * 16 + lr;
    aoff[f] = ra * 32 + ((kc ^ swz4(ra)) * 8);
  }
#pragma unroll
  for (int f = 0; f < 4; f++) {
    int rb_ = wn * 64 + f * 16 + lr;
    boff[f] = rb_ * 32 + ((kc ^ swz4(rb_)) * 8);
  }
  int bw[4];
#pragma unroll
  for (int j = 0; j < 4; j++)
    bw[j] = ((lane << 2) + j) * 32 + (((wv >> 1) ^ j ^ (lane & 3)) << 3) + ((wv & 1) << 2);

  int ntile = nyt[0] * (DDIM / 256) * 2;
  for (int t = blockIdx.x; t < ntile; t += gridDim.x) {
    int kh = t & 1, nx = (t >> 1) & 3, yt = t >> 3;
    int em = ytab[yt];
    int e = em >> 8, m0 = (em & 255) * 256, n0 = nx * 256;
    int cnt = counts[e];
    const float* Wf = (e < NEXP) ? (rw2 + (size_t)e * HDIM * DDIM) : sw2;
    const float* bias = (e < NEXP) ? (rb2 + (size_t)e * DDIM) : sb2;
    const int* list = lists + e * T_TOK;
    int seg = segoff[e];
    int k0 = kh * 1024;

    size_t abase[2];
#pragma unroll
    for (int j = 0; j < 2; j++)
      abase[j] = (size_t)(seg + min(m0 + srow[j], cnt - 1)) * HDIM + k0 + soff[j];
    const float* Wb = Wf + (size_t)k0 * DDIM + n0 + (lane << 2);

    f32x4 acc[8][4];
#pragma unroll
    for (int i = 0; i < 8; i++)
#pragma unroll
      for (int j = 0; j < 4; j++) acc[i][j] = (f32x4){0.f, 0.f, 0.f, 0.f};

    const int NS = 1024 / 32;   // 32 steps
    f32x4 vBa, vBb, vBc, vBd;
    {
      const float* Wk = Wb + (size_t)(wv * 4) * DDIM;
      vBa = *(const f32x4*)(Wk);
      vBb = *(const f32x4*)(Wk + DDIM);
      vBc = *(const f32x4*)(Wk + 2 * DDIM);
      vBd = *(const f32x4*)(Wk + 3 * DDIM);
    }
#pragma unroll
    for (int s = 0; s < 2; s++)
#pragma unroll
      for (int j = 0; j < 2; j++) {
        int i = j * 512 + tid;
        gload16(H1 + abase[j] + s * 32, &Alds[s][i * 8]);
      }

    for (int s = 0; s < NS; s++) {
      if (s + 2 < NS) {
        int kk = (s + 2) * 32;
        int nb = (s + 2) & 3;
#pragma unroll
        for (int j = 0; j < 2; j++) {
          int i = j * 512 + tid;
          gload16(H1 + abase[j] + kk, &Alds[nb][i * 8]);
        }
      }
      {
        u16* Bd = &Blds[s & 1][0];
#pragma unroll
        for (int j = 0; j < 4; j++) {
          u16x4 pk;
          pk[0] = f2bf(vBa[j]); pk[1] = f2bf(vBb[j]);
          pk[2] = f2bf(vBc[j]); pk[3] = f2bf(vBd[j]);
          *(u16x4*)(Bd + bw[j]) = pk;
        }
      }
      if (s + 1 < NS) {
        const float* Wk = Wb + (size_t)((s + 1) * 32 + wv * 4) * DDIM;
        vBa = *(const f32x4*)(Wk);
        vBb = *(const f32x4*)(Wk + DDIM);
        vBc = *(const f32x4*)(Wk + 2 * DDIM);
        vBd = *(const f32x4*)(Wk + 3 * DDIM);
      }
      if (s + 2 < NS)      asm volatile("s_waitcnt vmcnt(8)" ::: "memory");
      else if (s + 1 < NS) asm volatile("s_waitcnt vmcnt(6)" ::: "memory");
      else                 asm volatile("s_waitcnt vmcnt(0)" ::: "memory");
      asm volatile("s_waitcnt lgkmcnt(0)" ::: "memory");
      __builtin_amdgcn_s_barrier();
      __builtin_amdgcn_sched_barrier(0);

      const u16* Ac = &Alds[s & 3][0];
      const u16* Bc = &Blds[s & 1][0];
      bf16x8 af[8], bfr[4];
#pragma unroll
      for (int f = 0; f < 8; f++) af[f] = *(const bf16x8*)(Ac + aoff[f]);
#pragma unroll
      for (int f = 0; f < 4; f++) bfr[f] = *(const bf16x8*)(Bc + boff[f]);
      __builtin_amdgcn_s_setprio(1);
#pragma unroll
      for (int mf = 0; mf < 8; mf++)
#pragma unroll
        for (int nf = 0; nf < 4; nf++)
          acc[mf][nf] = __builtin_amdgcn_mfma_f32_16x16x32_bf16(af[mf], bfr[nf], acc[mf][nf], 0, 0, 0);
      __builtin_amdgcn_s_setprio(0);
    }

    float biasv[4];
#pragma unroll
    for (int nf = 0; nf < 4; nf++)
      biasv[nf] = (kh == 0) ? bias[n0 + wn * 64 + nf * 16 + lr] : 0.f;

#pragma unroll
    for (int mf = 0; mf < 8; mf++) {
#pragma unroll
      for (int rg = 0; rg < 4; rg++) {
        int mt = wm * 128 + mf * 16 + kc * 4 + rg;
        int mrow = m0 + mt;
        if (mrow < cnt) {
          int tok = list[mrow];
          float w = (e < NEXP) ? weights[(size_t)tok * NEXP + e] : 1.0f;
          float* orow = out + (size_t)tok * DDIM + n0 + wn * 64 + lr;
#pragma unroll
          for (int nf = 0; nf < 4; nf++)
            atomicAdd(orow + nf * 16, w * (acc[mf][nf][rg] + biasv[nf]));
        }
      }
    }
    __builtin_amdgcn_s_barrier();
    __builtin_amdgcn_sched_barrier(0);
  }
}

// ---------------- launcher ----------------
extern "C" void kernel_launch(void* const* d_in, const int* in_sizes, int n_in,
                              void* d_out, int out_size, void* d_ws, size_t ws_size,
                              hipStream_t stream) {
  (void)in_sizes; (void)n_in; (void)out_size; (void)ws_size;
  const float* hidden   = (const float*)d_in[0];
  const float* router_w = (const float*)d_in[1];
  const float* router_b = (const float*)d_in[2];
  const float* sw1 = (const float*)d_in[3];
  const float* sb1 = (const float*)d_in[4];
  const float* sw2 = (const float*)d_in[5];
  const float* sb2 = (const float*)d_in[6];
  const float* rw1 = (const float*)d_in[7];
  const float* rb1 = (const float*)d_in[8];
  const float* rw2 = (const float*)d_in[9];
  const float* rb2 = (const float*)d_in[10];
  float* out = (float*)d_out;

  char* ws = (char*)d_ws;
  u16* Xb      = (u16*)(ws + 0);            //  4,194,304  [T][D] bf16
  u16* H1      = (u16*)(ws + 4194304);      // 25,165,824  [6144][H] bf16
  float* weights = (float*)(ws + 29360128); //     65,536  [T][E]
  int* counts  = (int*)(ws + 29425664);     //         64
  int* segoff  = (int*)(ws + 29425728);     //         64
  int* lists   = (int*)(ws + 29425792);     //     73,728  [NSEG][T]
  int* ytab    = (int*)(ws + 29499520);     //        640
  int* nyt     = (int*)(ws + 29500160);     //          4

  hipMemsetAsync(counts, 0, 64, stream);
  hipMemsetAsync(out, 0, (size_t)T_TOK * DDIM * sizeof(float), stream);

  router_kernel<<<T_TOK / 4, 256, 0, stream>>>(hidden, router_w, router_b, Xb,
                                               weights, counts, lists);
  seg_kernel<<<1, 1, 0, stream>>>(counts, segoff, ytab, nyt);

  gemm1_kernel<<<512, 512, 0, stream>>>(
      Xb, rw1, sw1, rb1, sb1, counts, segoff, lists, ytab, nyt, H1);
  gemm2_kernel<<<256, 512, 0, stream>>>(
      H1, rw2, sw2, rb2, sb2, weights, counts, segoff, lists, ytab, nyt, out);
}